// Round 4
// baseline (423.954 us; speedup 1.0000x reference)
//
#include <hip/hip_runtime.h>
#include <hip/hip_bf16.h>

// Residual_Comb_Conv: B=2048, C_IN=64, C_MID=64, C_OUT=128, R=60, K=13
// R4: DENSE restructure. gather commutes with elementwise AND depends only on r,
// so with z stored as planes zT[r'][b][c] the gathered GEMM operand for (r,k)
// is the contiguous dense panel zT[nei[r,k]] -- no per-lane scatter at all.
// Pipeline (all on stream):
//   prep_p   : fold BN params -> params[]
//   prep_w   : W1->W1t[o][kk], W2|W3->W23t[o][kk] bf16 (kk = k*64+c)
//   t_in     : x[b][c][r] -> z1T/z3T[r][b][c] bf16 (act1/act3 applied)
//   gemm1    : per (r, btile): Out1[o,b] = W1t . z1T-panels; act2 -> z2T[r][b][o]
//   gemm2    : per (r, btile): Out[o,b] = W23t . [z2T|z3T]-panels (+cc) -> outT[r][b][o] bf16
//   t_out    : outT -> out[b][o][r] f32
// GEMM K-loops: no LDS, no barriers; fragments read directly from L2-resident
// panels; 1-iteration register prefetch.

typedef __attribute__((ext_vector_type(8))) short bf16x8;
typedef __attribute__((ext_vector_type(4))) float f32x4;
typedef __attribute__((ext_vector_type(4))) unsigned short us4;
typedef __attribute__((ext_vector_type(8))) unsigned short us8;

#define EPSV 1e-5f
#define PLANE 131072           // 2048*64 shorts per z plane
#define ZTOT  7864320          // 60*PLANE

__device__ __forceinline__ unsigned short f2bf(float f) {
  unsigned int u = __builtin_bit_cast(unsigned int, f);
  u += 0x7FFFu + ((u >> 16) & 1u);   // round-to-nearest-even
  return (unsigned short)(u >> 16);
}
__device__ __forceinline__ float bf2f(unsigned short s) {
  unsigned int u = ((unsigned int)s) << 16;
  return __builtin_bit_cast(float, u);
}

// ---- params: [a1|b1|a3|b3|a2|b2p] (6*64) + cc (128) = 512 floats
__global__ void prep_p(const float* __restrict__ g1, const float* __restrict__ be1,
                       const float* __restrict__ mu1, const float* __restrict__ va1,
                       const float* __restrict__ c1,
                       const float* __restrict__ g2, const float* __restrict__ be2,
                       const float* __restrict__ mu2, const float* __restrict__ va2,
                       const float* __restrict__ c2,
                       const float* __restrict__ g3, const float* __restrict__ be3,
                       const float* __restrict__ mu3, const float* __restrict__ va3,
                       const float* __restrict__ c3,
                       float* __restrict__ params) {
  int t = threadIdx.x;
  if (t < 64) {
    float a1v = g1[t] * rsqrtf(va1[t] + EPSV);
    params[t]       = a1v;
    params[64 + t]  = be1[t] - mu1[t] * a1v;
    float a3v = g3[t] * rsqrtf(va3[t] + EPSV);
    params[128 + t] = a3v;
    params[192 + t] = be3[t] - mu3[t] * a3v;
    float a2v = g2[t] * rsqrtf(va2[t] + EPSV);
    params[256 + t] = a2v;
    params[320 + t] = be2[t] - mu2[t] * a2v + a2v * c1[t];  // fold conv1 bias
  }
  if (t < 128) params[384 + t] = c2[t] + c3[t];
}

// ---- weights: W1 [64][64][13] -> W1t[o][kk=832], W2|W3 -> W23t[o][kk=1664]
__global__ void prep_w(const float* __restrict__ W1, const float* __restrict__ W2,
                       const float* __restrict__ W3, unsigned short* __restrict__ W1t,
                       unsigned short* __restrict__ W23t) {
  int t = blockIdx.x * 256 + threadIdx.x;
  if (t < 4096) {                        // W1: 64*64 (o,c) rows
    int o = t >> 6, c = t & 63;
    const float* src = W1 + (o * 64 + c) * 13;
    unsigned short* dst = W1t + o * 832 + c;
    #pragma unroll
    for (int ks = 0; ks < 13; ks++) dst[ks * 64] = f2bf(src[ks]);
  } else if (t < 20480) {                // W2,W3: 2*128*64 rows
    int idx = t - 4096;
    int half = idx >> 13;                // 0 -> W2, 1 -> W3
    int o = (idx >> 6) & 127, c = idx & 63;
    const float* src = (half ? W3 : W2) + (o * 64 + c) * 13;
    unsigned short* dst = W23t + o * 1664 + half * 13 * 64 + c;
    #pragma unroll
    for (int ks = 0; ks < 13; ks++) dst[ks * 64] = f2bf(src[ks]);
  }
}

// ---- transpose-in: x[b][c][r] f32 -> z1T/z3T[r][b][c] bf16 with act1/act3
__global__ __launch_bounds__(256) void t_in(const float* __restrict__ x,
                                            const float* __restrict__ params,
                                            unsigned short* __restrict__ z1T,
                                            unsigned short* __restrict__ z3T) {
  __shared__ float xt[64 * 61];
  __shared__ float prm[256];
  const int b = blockIdx.x, t = threadIdx.x;
  prm[t] = params[t];                       // a1|b1|a3|b3
  for (int i = t; i < 3840; i += 256) {
    int c = i / 60;
    xt[c * 61 + (i - c * 60)] = x[b * 3840 + i];
  }
  __syncthreads();
  if (t < 240) {
    int r = t >> 2, g = t & 3, c0 = g << 4;
    us8 z1v0, z1v1, z3v0, z3v1;
    #pragma unroll
    for (int j = 0; j < 8; j++) {
      int c = c0 + j;
      float v = xt[c * 61 + r];
      z1v0[j] = f2bf(fmaxf(fmaf(v, prm[c], prm[64 + c]), 0.f));
      z3v0[j] = f2bf(fmaxf(fmaf(v, prm[128 + c], prm[192 + c]), 0.f));
    }
    #pragma unroll
    for (int j = 0; j < 8; j++) {
      int c = c0 + 8 + j;
      float v = xt[c * 61 + r];
      z1v1[j] = f2bf(fmaxf(fmaf(v, prm[c], prm[64 + c]), 0.f));
      z3v1[j] = f2bf(fmaxf(fmaf(v, prm[128 + c], prm[192 + c]), 0.f));
    }
    int idx = (r * 2048 + b) * 64 + c0;
    *(us8*)(z1T + idx) = z1v0;  *(us8*)(z1T + idx + 8) = z1v1;
    *(us8*)(z3T + idx) = z3v0;  *(us8*)(z3T + idx + 8) = z3v1;
  }
}

#define MFMA __builtin_amdgcn_mfma_f32_16x16x32_bf16

// ---- gemm1: per (r, btile=128): [64o x 128b] = W1t[64x832] . panels(z1T)
//      wave = (mh, nh): 2 mtiles x 4 ntiles. No LDS, no barriers.
__global__ __launch_bounds__(256, 3) void gemm1(const unsigned short* __restrict__ W1t,
                                                const unsigned short* __restrict__ z1T,
                                                const int* __restrict__ nei,
                                                const float* __restrict__ params,
                                                unsigned short* __restrict__ z2T) {
  const int bid = blockIdx.x;
  const int r = bid >> 4, b0 = (bid & 15) << 7;
  const int t = threadIdx.x, wave = t >> 6, lane = t & 63;
  const int quad = lane >> 4, nl = lane & 15;
  const int mh = wave >> 1, nh = wave & 1;

  int pl[13];
  #pragma unroll
  for (int q = 0; q < 13; q++) pl[q] = nei[r * 13 + q];

  const unsigned short* wA0 = W1t + (mh * 32 + nl) * 832;
  const unsigned short* wA1 = wA0 + 16 * 832;
  const unsigned short* zb  = z1T + (b0 + nh * 64 + nl) * 64;

  f32x4 acc[2][4] = {};
  int koff = quad * 8;                    // ks=0: q=0,s=0
  bf16x8 A0 = *(const bf16x8*)(wA0 + koff);
  bf16x8 A1 = *(const bf16x8*)(wA1 + koff);
  const unsigned short* zp = zb + pl[0] * PLANE + koff;
  bf16x8 B0 = *(const bf16x8*)(zp);
  bf16x8 B1 = *(const bf16x8*)(zp + 1024);
  bf16x8 B2 = *(const bf16x8*)(zp + 2048);
  bf16x8 B3 = *(const bf16x8*)(zp + 3072);

  #pragma unroll 1
  for (int ks = 0; ks < 26; ks++) {
    int ksn = (ks < 25) ? ks + 1 : 25;
    int qn = ksn >> 1, sn = ksn & 1;
    int koffn = qn * 64 + sn * 32 + quad * 8;
    bf16x8 nA0 = *(const bf16x8*)(wA0 + koffn);
    bf16x8 nA1 = *(const bf16x8*)(wA1 + koffn);
    const unsigned short* zpn = zb + pl[qn] * PLANE + sn * 32 + quad * 8;
    bf16x8 nB0 = *(const bf16x8*)(zpn);
    bf16x8 nB1 = *(const bf16x8*)(zpn + 1024);
    bf16x8 nB2 = *(const bf16x8*)(zpn + 2048);
    bf16x8 nB3 = *(const bf16x8*)(zpn + 3072);
    acc[0][0] = MFMA(A0, B0, acc[0][0], 0, 0, 0);
    acc[0][1] = MFMA(A0, B1, acc[0][1], 0, 0, 0);
    acc[0][2] = MFMA(A0, B2, acc[0][2], 0, 0, 0);
    acc[0][3] = MFMA(A0, B3, acc[0][3], 0, 0, 0);
    acc[1][0] = MFMA(A1, B0, acc[1][0], 0, 0, 0);
    acc[1][1] = MFMA(A1, B1, acc[1][1], 0, 0, 0);
    acc[1][2] = MFMA(A1, B2, acc[1][2], 0, 0, 0);
    acc[1][3] = MFMA(A1, B3, acc[1][3], 0, 0, 0);
    A0 = nA0; A1 = nA1; B0 = nB0; B1 = nB1; B2 = nB2; B3 = nB3;
  }

  // act2 -> z2T[r][b][o]
  #pragma unroll
  for (int mt = 0; mt < 2; mt++) {
    int o = mh * 32 + mt * 16 + quad * 4;
    f32x4 av = *(const f32x4*)(params + 256 + o);
    f32x4 bv = *(const f32x4*)(params + 320 + o);
    #pragma unroll
    for (int nt = 0; nt < 4; nt++) {
      int bcol = b0 + nh * 64 + nt * 16 + nl;
      f32x4 a = acc[mt][nt];
      us4 w;
      w.x = f2bf(fmaxf(fmaf(a[0], av[0], bv[0]), 0.f));
      w.y = f2bf(fmaxf(fmaf(a[1], av[1], bv[1]), 0.f));
      w.z = f2bf(fmaxf(fmaf(a[2], av[2], bv[2]), 0.f));
      w.w = f2bf(fmaxf(fmaf(a[3], av[3], bv[3]), 0.f));
      *(us4*)(z2T + (r * 2048 + bcol) * 64 + o) = w;
    }
  }
}

// ---- gemm2: per (r, btile=128): [128o x 128b] = W23t[128x1664] . [z2T|z3T panels]
//      wave = (mh, nh): 4 mtiles x 4 ntiles.
__global__ __launch_bounds__(256, 3) void gemm2(const unsigned short* __restrict__ W23t,
                                                const unsigned short* __restrict__ z2T,
                                                const unsigned short* __restrict__ z3T,
                                                const int* __restrict__ nei,
                                                const float* __restrict__ params,
                                                unsigned short* __restrict__ outT) {
  const int bid = blockIdx.x;
  const int r = bid >> 4, b0 = (bid & 15) << 7;
  const int t = threadIdx.x, wave = t >> 6, lane = t & 63;
  const int quad = lane >> 4, nl = lane & 15;
  const int mh = wave >> 1, nh = wave & 1;

  int pl[13];
  #pragma unroll
  for (int q = 0; q < 13; q++) pl[q] = nei[r * 13 + q];

  const unsigned short* wA0 = W23t + (mh * 64 + nl) * 1664;
  const unsigned short* wA1 = wA0 + 16 * 1664;
  const unsigned short* wA2 = wA0 + 32 * 1664;
  const unsigned short* wA3 = wA0 + 48 * 1664;
  const int coloff = (b0 + nh * 64 + nl) * 64;

  f32x4 acc[4][4] = {};
  int koff = quad * 8;
  bf16x8 A0 = *(const bf16x8*)(wA0 + koff);
  bf16x8 A1 = *(const bf16x8*)(wA1 + koff);
  bf16x8 A2 = *(const bf16x8*)(wA2 + koff);
  bf16x8 A3 = *(const bf16x8*)(wA3 + koff);
  const unsigned short* zp = z2T + coloff + pl[0] * PLANE + koff;
  bf16x8 B0 = *(const bf16x8*)(zp);
  bf16x8 B1 = *(const bf16x8*)(zp + 1024);
  bf16x8 B2 = *(const bf16x8*)(zp + 2048);
  bf16x8 B3 = *(const bf16x8*)(zp + 3072);

  #pragma unroll 1
  for (int ks = 0; ks < 52; ks++) {
    int ksn = (ks < 51) ? ks + 1 : 51;
    int qn = ksn >> 1, sn = ksn & 1;
    int koffn = qn * 64 + sn * 32 + quad * 8;
    bf16x8 nA0 = *(const bf16x8*)(wA0 + koffn);
    bf16x8 nA1 = *(const bf16x8*)(wA1 + koffn);
    bf16x8 nA2 = *(const bf16x8*)(wA2 + koffn);
    bf16x8 nA3 = *(const bf16x8*)(wA3 + koffn);
    int qq = (qn < 13) ? qn : qn - 13;
    const unsigned short* zsrc = (qn < 13) ? z2T : z3T;
    const unsigned short* zpn = zsrc + coloff + pl[qq] * PLANE + sn * 32 + quad * 8;
    bf16x8 nB0 = *(const bf16x8*)(zpn);
    bf16x8 nB1 = *(const bf16x8*)(zpn + 1024);
    bf16x8 nB2 = *(const bf16x8*)(zpn + 2048);
    bf16x8 nB3 = *(const bf16x8*)(zpn + 3072);
    acc[0][0] = MFMA(A0, B0, acc[0][0], 0, 0, 0);
    acc[0][1] = MFMA(A0, B1, acc[0][1], 0, 0, 0);
    acc[0][2] = MFMA(A0, B2, acc[0][2], 0, 0, 0);
    acc[0][3] = MFMA(A0, B3, acc[0][3], 0, 0, 0);
    acc[1][0] = MFMA(A1, B0, acc[1][0], 0, 0, 0);
    acc[1][1] = MFMA(A1, B1, acc[1][1], 0, 0, 0);
    acc[1][2] = MFMA(A1, B2, acc[1][2], 0, 0, 0);
    acc[1][3] = MFMA(A1, B3, acc[1][3], 0, 0, 0);
    acc[2][0] = MFMA(A2, B0, acc[2][0], 0, 0, 0);
    acc[2][1] = MFMA(A2, B1, acc[2][1], 0, 0, 0);
    acc[2][2] = MFMA(A2, B2, acc[2][2], 0, 0, 0);
    acc[2][3] = MFMA(A2, B3, acc[2][3], 0, 0, 0);
    acc[3][0] = MFMA(A3, B0, acc[3][0], 0, 0, 0);
    acc[3][1] = MFMA(A3, B1, acc[3][1], 0, 0, 0);
    acc[3][2] = MFMA(A3, B2, acc[3][2], 0, 0, 0);
    acc[3][3] = MFMA(A3, B3, acc[3][3], 0, 0, 0);
    A0 = nA0; A1 = nA1; A2 = nA2; A3 = nA3;
    B0 = nB0; B1 = nB1; B2 = nB2; B3 = nB3;
  }

  // + cc -> outT[r][b][o] bf16
  #pragma unroll
  for (int mt = 0; mt < 4; mt++) {
    int o = mh * 64 + mt * 16 + quad * 4;
    f32x4 cv = *(const f32x4*)(params + 384 + o);
    #pragma unroll
    for (int nt = 0; nt < 4; nt++) {
      int bcol = b0 + nh * 64 + nt * 16 + nl;
      f32x4 a = acc[mt][nt];
      us4 w;
      w.x = f2bf(a[0] + cv[0]);
      w.y = f2bf(a[1] + cv[1]);
      w.z = f2bf(a[2] + cv[2]);
      w.w = f2bf(a[3] + cv[3]);
      *(us4*)(outT + (r * 2048 + bcol) * 128 + o) = w;
    }
  }
}

// ---- transpose-out: outT[r][b][o] bf16 -> out[b][o][r] f32
__global__ __launch_bounds__(256) void t_out(const unsigned short* __restrict__ outT,
                                             float* __restrict__ out) {
  __shared__ float ot[60 * 129];
  const int b = blockIdx.x, t = threadIdx.x;
  for (int i = t; i < 1920; i += 256) {
    int r = i >> 5, og = (i & 31) << 2;
    us4 v = *(const us4*)(outT + (r * 2048 + b) * 128 + og);
    ot[r * 129 + og + 0] = bf2f(v.x);
    ot[r * 129 + og + 1] = bf2f(v.y);
    ot[r * 129 + og + 2] = bf2f(v.z);
    ot[r * 129 + og + 3] = bf2f(v.w);
  }
  __syncthreads();
  int o = t >> 1, s = t & 1;
  float* dst = out + b * 7680 + o * 60 + s * 30;
  #pragma unroll
  for (int j = 0; j < 30; j++) dst[j] = ot[(s * 30 + j) * 129 + o];
}

extern "C" void kernel_launch(void* const* d_in, const int* in_sizes, int n_in,
                              void* d_out, int out_size, void* d_ws, size_t ws_size,
                              hipStream_t stream) {
  const float* x   = (const float*)d_in[0];
  const int*   nei = (const int*)d_in[1];
  const float* g1  = (const float*)d_in[2];
  const float* be1 = (const float*)d_in[3];
  const float* mu1 = (const float*)d_in[4];
  const float* va1 = (const float*)d_in[5];
  const float* W1  = (const float*)d_in[6];
  const float* c1  = (const float*)d_in[7];
  const float* g2  = (const float*)d_in[8];
  const float* be2 = (const float*)d_in[9];
  const float* mu2 = (const float*)d_in[10];
  const float* va2 = (const float*)d_in[11];
  const float* W2  = (const float*)d_in[12];
  const float* c2  = (const float*)d_in[13];
  const float* g3  = (const float*)d_in[14];
  const float* be3 = (const float*)d_in[15];
  const float* mu3 = (const float*)d_in[16];
  const float* va3 = (const float*)d_in[17];
  const float* W3  = (const float*)d_in[18];
  const float* c3  = (const float*)d_in[19];

  // ws layout (63.5 MB): W1t | W23t | params | z2T | z3T | big(z1T ∪ outT)
  unsigned short* W1t  = (unsigned short*)d_ws;
  unsigned short* W23t = W1t + 53248;
  float*          prm  = (float*)(W23t + 212992);
  unsigned short* z2T  = (unsigned short*)(prm + 512);
  unsigned short* z3T  = z2T + ZTOT;
  unsigned short* big  = z3T + ZTOT;       // z1T (read in gemm1) aliases outT (written in gemm2)
  unsigned short* z1T  = big;
  unsigned short* outT = big;

  prep_p<<<1, 128, 0, stream>>>(g1, be1, mu1, va1, c1, g2, be2, mu2, va2, c2,
                                g3, be3, mu3, va3, c3, prm);
  prep_w<<<80, 256, 0, stream>>>(W1, W2, W3, W1t, W23t);
  t_in<<<2048, 256, 0, stream>>>(x, prm, z1T, z3T);
  gemm1<<<960, 256, 0, stream>>>(W1t, z1T, nei, prm, z2T);
  gemm2<<<960, 256, 0, stream>>>(W23t, z2T, z3T, nei, prm, outT);
  t_out<<<2048, 256, 0, stream>>>(outT, (float*)d_out);
}

// Round 5
// 259.216 us; speedup vs baseline: 1.6355x; 1.6355x over previous
//
#include <hip/hip_runtime.h>
#include <hip/hip_bf16.h>

// Residual_Comb_Conv: B=2048, C_IN=64, C_MID=64, C_OUT=128, R=60, K=13
// R5: dense-panel GEMMs (R4 formulation) + m97-style LDS double-buffered
// K-loop (R4's no-LDS fragments exposed raw L2 latency every read: 64 VGPRs
// couldn't hold the prefetch, ~2500+ cyc/iter). Staging: global->reg->LDS,
// vmcnt wait covered by the MFMA window; fragments from LDS (padded rows,
// uniform bank-group spread). One barrier per K-step, double-buffered.
//   prep_p : fold BN params
//   prep_w : W1->W1t[o][kk], W2|W3->W23t[o][kk] bf16 (kk = k*64+c)
//   t_in   : x[b][c][r] -> z1T/z3T[r][b][c] bf16 (act1/act3 applied)
//   gemm1  : per (btile,r): [64 x 128] = W1t . z1T-panels; act2 -> z2T
//   gemm2  : per (btile,r): [128 x 128] = W23t . [z2T|z3T]-panels + cc -> outT
//   t_out  : outT[r][b][o] bf16 -> out[b][o][r] f32

typedef __attribute__((ext_vector_type(8))) short bf16x8;
typedef __attribute__((ext_vector_type(4))) float f32x4;
typedef __attribute__((ext_vector_type(4))) unsigned short us4;
typedef __attribute__((ext_vector_type(8))) unsigned short us8;

#define EPSV 1e-5f
#define PLANE 131072           // 2048*64 shorts per z plane
#define ZTOT  7864320          // 60*PLANE
#define LDSTR 72               // LDS row stride in shorts (64 + 8 pad)

__device__ __forceinline__ unsigned short f2bf(float f) {
  unsigned int u = __builtin_bit_cast(unsigned int, f);
  u += 0x7FFFu + ((u >> 16) & 1u);   // round-to-nearest-even
  return (unsigned short)(u >> 16);
}
__device__ __forceinline__ float bf2f(unsigned short s) {
  unsigned int u = ((unsigned int)s) << 16;
  return __builtin_bit_cast(float, u);
}

// ---- params: [a1|b1|a3|b3|a2|b2p] (6*64) + cc (128) = 512 floats
__global__ void prep_p(const float* __restrict__ g1, const float* __restrict__ be1,
                       const float* __restrict__ mu1, const float* __restrict__ va1,
                       const float* __restrict__ c1,
                       const float* __restrict__ g2, const float* __restrict__ be2,
                       const float* __restrict__ mu2, const float* __restrict__ va2,
                       const float* __restrict__ c2,
                       const float* __restrict__ g3, const float* __restrict__ be3,
                       const float* __restrict__ mu3, const float* __restrict__ va3,
                       const float* __restrict__ c3,
                       float* __restrict__ params) {
  int t = threadIdx.x;
  if (t < 64) {
    float a1v = g1[t] * rsqrtf(va1[t] + EPSV);
    params[t]       = a1v;
    params[64 + t]  = be1[t] - mu1[t] * a1v;
    float a3v = g3[t] * rsqrtf(va3[t] + EPSV);
    params[128 + t] = a3v;
    params[192 + t] = be3[t] - mu3[t] * a3v;
    float a2v = g2[t] * rsqrtf(va2[t] + EPSV);
    params[256 + t] = a2v;
    params[320 + t] = be2[t] - mu2[t] * a2v + a2v * c1[t];  // fold conv1 bias
  }
  if (t < 128) params[384 + t] = c2[t] + c3[t];
}

// ---- weights: W1 [64][64][13] -> W1t[o][kk=832], W2|W3 -> W23t[o][kk=1664]
__global__ void prep_w(const float* __restrict__ W1, const float* __restrict__ W2,
                       const float* __restrict__ W3, unsigned short* __restrict__ W1t,
                       unsigned short* __restrict__ W23t) {
  int t = blockIdx.x * 256 + threadIdx.x;
  if (t < 4096) {                        // W1: 64*64 (o,c) rows
    int o = t >> 6, c = t & 63;
    const float* src = W1 + (o * 64 + c) * 13;
    unsigned short* dst = W1t + o * 832 + c;
    #pragma unroll
    for (int ks = 0; ks < 13; ks++) dst[ks * 64] = f2bf(src[ks]);
  } else if (t < 20480) {                // W2,W3: 2*128*64 rows
    int idx = t - 4096;
    int half = idx >> 13;                // 0 -> W2, 1 -> W3
    int o = (idx >> 6) & 127, c = idx & 63;
    const float* src = (half ? W3 : W2) + (o * 64 + c) * 13;
    unsigned short* dst = W23t + o * 1664 + half * 13 * 64 + c;
    #pragma unroll
    for (int ks = 0; ks < 13; ks++) dst[ks * 64] = f2bf(src[ks]);
  }
}

// ---- transpose-in: x[b][c][r] f32 -> z1T/z3T[r][b][c] bf16 with act1/act3
__global__ __launch_bounds__(256) void t_in(const float* __restrict__ x,
                                            const float* __restrict__ params,
                                            unsigned short* __restrict__ z1T,
                                            unsigned short* __restrict__ z3T) {
  __shared__ float xt[64 * 61];
  __shared__ float prm[256];
  const int b = blockIdx.x, t = threadIdx.x;
  prm[t] = params[t];                       // a1|b1|a3|b3
  for (int i = t; i < 3840; i += 256) {
    int c = i / 60;
    xt[c * 61 + (i - c * 60)] = x[b * 3840 + i];
  }
  __syncthreads();
  if (t < 240) {
    int r = t >> 2, g = t & 3, c0 = g << 4;
    us8 z1v0, z1v1, z3v0, z3v1;
    #pragma unroll
    for (int j = 0; j < 8; j++) {
      int c = c0 + j;
      float v = xt[c * 61 + r];
      z1v0[j] = f2bf(fmaxf(fmaf(v, prm[c], prm[64 + c]), 0.f));
      z3v0[j] = f2bf(fmaxf(fmaf(v, prm[128 + c], prm[192 + c]), 0.f));
    }
    #pragma unroll
    for (int j = 0; j < 8; j++) {
      int c = c0 + 8 + j;
      float v = xt[c * 61 + r];
      z1v1[j] = f2bf(fmaxf(fmaf(v, prm[c], prm[64 + c]), 0.f));
      z3v1[j] = f2bf(fmaxf(fmaf(v, prm[128 + c], prm[192 + c]), 0.f));
    }
    int idx = (r * 2048 + b) * 64 + c0;
    *(us8*)(z1T + idx) = z1v0;  *(us8*)(z1T + idx + 8) = z1v1;
    *(us8*)(z3T + idx) = z3v0;  *(us8*)(z3T + idx + 8) = z3v1;
  }
}

#define MFMA __builtin_amdgcn_mfma_f32_16x16x32_bf16

// ---- gemm1: per (btile,r): C[64 x 128] = W1t[64x832] . z1T-panels
//      4 waves: (mh = wave>>1) rows mh*32+{0,16}, (nh = wave&1) cols nh*64+{0..3}*16
__global__ __launch_bounds__(256, 2) void gemm1(const unsigned short* __restrict__ W1t,
                                                const unsigned short* __restrict__ z1T,
                                                const int* __restrict__ nei,
                                                const float* __restrict__ params,
                                                unsigned short* __restrict__ z2T) {
  __shared__ unsigned short As[2][64 * LDSTR];
  __shared__ unsigned short Bs[2][128 * LDSTR];

  const int bid = blockIdx.x;
  const int btile = bid / 60, r = bid - btile * 60;
  const int b0 = btile << 7;
  const int t = threadIdx.x, wave = t >> 6, lane = t & 63;
  const int quad = lane >> 4, nl = lane & 15;
  const int mh = wave >> 1, nh = wave & 1;

  int pl[13];
  #pragma unroll
  for (int q = 0; q < 13; q++) pl[q] = nei[r * 13 + q];

  const int trow = t >> 3, tj = t & 7;             // staging: 16B chunk (row=trow+i*32, j=tj)
  const unsigned short* gA = W1t + trow * 832 + tj * 8;
  const unsigned short* gB = z1T + (b0 + trow) * 64 + tj * 8;
  unsigned short* lA = &As[0][0] + trow * LDSTR + tj * 8;
  unsigned short* lB = &Bs[0][0] + trow * LDSTR + tj * 8;

  // stage kq=0 into buffer 0
  {
    us8 va0 = *(const us8*)(gA);
    us8 va1 = *(const us8*)(gA + 32 * 832);
    const unsigned short* gb = gB + pl[0] * PLANE;
    us8 vb0 = *(const us8*)(gb);
    us8 vb1 = *(const us8*)(gb + 2048);
    us8 vb2 = *(const us8*)(gb + 4096);
    us8 vb3 = *(const us8*)(gb + 6144);
    *(us8*)(lA) = va0;
    *(us8*)(lA + 32 * LDSTR) = va1;
    *(us8*)(lB) = vb0;
    *(us8*)(lB + 32 * LDSTR) = vb1;
    *(us8*)(lB + 64 * LDSTR) = vb2;
    *(us8*)(lB + 96 * LDSTR) = vb3;
  }
  __syncthreads();

  f32x4 acc[2][4] = {};
  #pragma unroll 1
  for (int kq = 0; kq < 13; kq++) {
    const int bf = kq & 1;
    us8 va0, va1, vb0, vb1, vb2, vb3;
    if (kq < 12) {                                 // global loads for kq+1
      const unsigned short* ga = gA + (kq + 1) * 64;
      va0 = *(const us8*)(ga);
      va1 = *(const us8*)(ga + 32 * 832);
      const unsigned short* gb = gB + pl[kq + 1] * PLANE;
      vb0 = *(const us8*)(gb);
      vb1 = *(const us8*)(gb + 2048);
      vb2 = *(const us8*)(gb + 4096);
      vb3 = *(const us8*)(gb + 6144);
    }
    // compute on buffer bf
    const unsigned short* Ab = &As[bf][0] + (mh * 32 + nl) * LDSTR + quad * 8;
    const unsigned short* Bb = &Bs[bf][0] + (nh * 64 + nl) * LDSTR + quad * 8;
    bf16x8 af[2][2], bfr[4][2];
    #pragma unroll
    for (int mt = 0; mt < 2; mt++) {
      af[mt][0] = *(const bf16x8*)(Ab + mt * 16 * LDSTR);
      af[mt][1] = *(const bf16x8*)(Ab + mt * 16 * LDSTR + 32);
    }
    #pragma unroll
    for (int nt = 0; nt < 4; nt++) {
      bfr[nt][0] = *(const bf16x8*)(Bb + nt * 16 * LDSTR);
      bfr[nt][1] = *(const bf16x8*)(Bb + nt * 16 * LDSTR + 32);
    }
    #pragma unroll
    for (int h = 0; h < 2; h++) {
      #pragma unroll
      for (int mt = 0; mt < 2; mt++) {
        #pragma unroll
        for (int nt = 0; nt < 4; nt++) {
          acc[mt][nt] = MFMA(af[mt][h], bfr[nt][h], acc[mt][nt], 0, 0, 0);
        }
      }
    }
    if (kq < 12) {                                 // write kq+1 into other buffer
      unsigned short* la = lA + (bf ^ 1) * (64 * LDSTR);
      unsigned short* lb = lB + (bf ^ 1) * (128 * LDSTR);
      *(us8*)(la) = va0;
      *(us8*)(la + 32 * LDSTR) = va1;
      *(us8*)(lb) = vb0;
      *(us8*)(lb + 32 * LDSTR) = vb1;
      *(us8*)(lb + 64 * LDSTR) = vb2;
      *(us8*)(lb + 96 * LDSTR) = vb3;
    }
    __syncthreads();
  }

  // epilogue: act2 -> z2T[r][b][o]
  #pragma unroll
  for (int mt = 0; mt < 2; mt++) {
    int ob = mh * 32 + mt * 16 + quad * 4;
    f32x4 av = *(const f32x4*)(params + 256 + ob);
    f32x4 bv = *(const f32x4*)(params + 320 + ob);
    #pragma unroll
    for (int nt = 0; nt < 4; nt++) {
      int col = b0 + nh * 64 + nt * 16 + nl;
      f32x4 a = acc[mt][nt];
      us4 w;
      w.x = f2bf(fmaxf(fmaf(a[0], av[0], bv[0]), 0.f));
      w.y = f2bf(fmaxf(fmaf(a[1], av[1], bv[1]), 0.f));
      w.z = f2bf(fmaxf(fmaf(a[2], av[2], bv[2]), 0.f));
      w.w = f2bf(fmaxf(fmaf(a[3], av[3], bv[3]), 0.f));
      *(us4*)(z2T + (r * 2048 + col) * 64 + ob) = w;
    }
  }
}

// ---- gemm2: per (btile,r): C[128 x 128] = W23t[128x1664] . [z2T|z3T]-panels + cc
//      4 waves: rows mh*64 + {0..3}*16, cols nh*64 + {0..3}*16
__global__ __launch_bounds__(256, 2) void gemm2(const unsigned short* __restrict__ W23t,
                                                const unsigned short* __restrict__ z2T,
                                                const unsigned short* __restrict__ z3T,
                                                const int* __restrict__ nei,
                                                const float* __restrict__ params,
                                                unsigned short* __restrict__ outT) {
  __shared__ unsigned short As[2][128 * LDSTR];
  __shared__ unsigned short Bs[2][128 * LDSTR];

  const int bid = blockIdx.x;
  const int btile = bid / 60, r = bid - btile * 60;
  const int b0 = btile << 7;
  const int t = threadIdx.x, wave = t >> 6, lane = t & 63;
  const int quad = lane >> 4, nl = lane & 15;
  const int mh = wave >> 1, nh = wave & 1;

  int pl[13];
  #pragma unroll
  for (int q = 0; q < 13; q++) pl[q] = nei[r * 13 + q];

  const int trow = t >> 3, tj = t & 7;
  const unsigned short* gA  = W23t + trow * 1664 + tj * 8;
  const unsigned short* gB2 = z2T + (b0 + trow) * 64 + tj * 8;
  const unsigned short* gB3 = z3T + (b0 + trow) * 64 + tj * 8;
  unsigned short* lA = &As[0][0] + trow * LDSTR + tj * 8;
  unsigned short* lB = &Bs[0][0] + trow * LDSTR + tj * 8;

  // stage kq=0 into buffer 0
  {
    us8 va0 = *(const us8*)(gA);
    us8 va1 = *(const us8*)(gA + 32 * 1664);
    us8 va2 = *(const us8*)(gA + 64 * 1664);
    us8 va3 = *(const us8*)(gA + 96 * 1664);
    const unsigned short* gb = gB2 + pl[0] * PLANE;
    us8 vb0 = *(const us8*)(gb);
    us8 vb1 = *(const us8*)(gb + 2048);
    us8 vb2 = *(const us8*)(gb + 4096);
    us8 vb3 = *(const us8*)(gb + 6144);
    *(us8*)(lA) = va0;
    *(us8*)(lA + 32 * LDSTR) = va1;
    *(us8*)(lA + 64 * LDSTR) = va2;
    *(us8*)(lA + 96 * LDSTR) = va3;
    *(us8*)(lB) = vb0;
    *(us8*)(lB + 32 * LDSTR) = vb1;
    *(us8*)(lB + 64 * LDSTR) = vb2;
    *(us8*)(lB + 96 * LDSTR) = vb3;
  }
  __syncthreads();

  f32x4 acc[4][4] = {};
  #pragma unroll 1
  for (int kq = 0; kq < 26; kq++) {
    const int bf = kq & 1;
    us8 va0, va1, va2, va3, vb0, vb1, vb2, vb3;
    if (kq < 25) {                                 // global loads for kq+1
      const int kn = kq + 1;
      const unsigned short* ga = gA + kn * 64;
      va0 = *(const us8*)(ga);
      va1 = *(const us8*)(ga + 32 * 1664);
      va2 = *(const us8*)(ga + 64 * 1664);
      va3 = *(const us8*)(ga + 96 * 1664);
      const unsigned short* gb = (kn < 13) ? (gB2 + pl[kn] * PLANE)
                                           : (gB3 + pl[kn - 13] * PLANE);
      vb0 = *(const us8*)(gb);
      vb1 = *(const us8*)(gb + 2048);
      vb2 = *(const us8*)(gb + 4096);
      vb3 = *(const us8*)(gb + 6144);
    }
    // compute on buffer bf
    const unsigned short* Ab = &As[bf][0] + (mh * 64 + nl) * LDSTR + quad * 8;
    const unsigned short* Bb = &Bs[bf][0] + (nh * 64 + nl) * LDSTR + quad * 8;
    bf16x8 af[4][2], bfr[4][2];
    #pragma unroll
    for (int mt = 0; mt < 4; mt++) {
      af[mt][0] = *(const bf16x8*)(Ab + mt * 16 * LDSTR);
      af[mt][1] = *(const bf16x8*)(Ab + mt * 16 * LDSTR + 32);
    }
    #pragma unroll
    for (int nt = 0; nt < 4; nt++) {
      bfr[nt][0] = *(const bf16x8*)(Bb + nt * 16 * LDSTR);
      bfr[nt][1] = *(const bf16x8*)(Bb + nt * 16 * LDSTR + 32);
    }
    #pragma unroll
    for (int h = 0; h < 2; h++) {
      #pragma unroll
      for (int mt = 0; mt < 4; mt++) {
        #pragma unroll
        for (int nt = 0; nt < 4; nt++) {
          acc[mt][nt] = MFMA(af[mt][h], bfr[nt][h], acc[mt][nt], 0, 0, 0);
        }
      }
    }
    if (kq < 25) {                                 // write kq+1 into other buffer
      unsigned short* la = lA + (bf ^ 1) * (128 * LDSTR);
      unsigned short* lb = lB + (bf ^ 1) * (128 * LDSTR);
      *(us8*)(la) = va0;
      *(us8*)(la + 32 * LDSTR) = va1;
      *(us8*)(la + 64 * LDSTR) = va2;
      *(us8*)(la + 96 * LDSTR) = va3;
      *(us8*)(lb) = vb0;
      *(us8*)(lb + 32 * LDSTR) = vb1;
      *(us8*)(lb + 64 * LDSTR) = vb2;
      *(us8*)(lb + 96 * LDSTR) = vb3;
    }
    __syncthreads();
  }

  // epilogue: + cc -> outT[r][b][o] bf16
  #pragma unroll
  for (int mt = 0; mt < 4; mt++) {
    int ob = mh * 64 + mt * 16 + quad * 4;
    f32x4 cv = *(const f32x4*)(params + 384 + ob);
    #pragma unroll
    for (int nt = 0; nt < 4; nt++) {
      int col = b0 + nh * 64 + nt * 16 + nl;
      f32x4 a = acc[mt][nt];
      us4 w;
      w.x = f2bf(a[0] + cv[0]);
      w.y = f2bf(a[1] + cv[1]);
      w.z = f2bf(a[2] + cv[2]);
      w.w = f2bf(a[3] + cv[3]);
      *(us4*)(outT + (r * 2048 + col) * 128 + ob) = w;
    }
  }
}

// ---- transpose-out: outT[r][b][o] bf16 -> out[b][o][r] f32
__global__ __launch_bounds__(256) void t_out(const unsigned short* __restrict__ outT,
                                             float* __restrict__ out) {
  __shared__ float ot[60 * 129];
  const int b = blockIdx.x, t = threadIdx.x;
  for (int i = t; i < 1920; i += 256) {
    int r = i >> 5, og = (i & 31) << 2;
    us4 v = *(const us4*)(outT + (r * 2048 + b) * 128 + og);
    ot[r * 129 + og + 0] = bf2f(v.x);
    ot[r * 129 + og + 1] = bf2f(v.y);
    ot[r * 129 + og + 2] = bf2f(v.z);
    ot[r * 129 + og + 3] = bf2f(v.w);
  }
  __syncthreads();
  int o = t >> 1, s = t & 1;
  float* dst = out + b * 7680 + o * 60 + s * 30;
  #pragma unroll
  for (int j = 0; j < 30; j++) dst[j] = ot[(s * 30 + j) * 129 + o];
}

extern "C" void kernel_launch(void* const* d_in, const int* in_sizes, int n_in,
                              void* d_out, int out_size, void* d_ws, size_t ws_size,
                              hipStream_t stream) {
  const float* x   = (const float*)d_in[0];
  const int*   nei = (const int*)d_in[1];
  const float* g1  = (const float*)d_in[2];
  const float* be1 = (const float*)d_in[3];
  const float* mu1 = (const float*)d_in[4];
  const float* va1 = (const float*)d_in[5];
  const float* W1  = (const float*)d_in[6];
  const float* c1  = (const float*)d_in[7];
  const float* g2  = (const float*)d_in[8];
  const float* be2 = (const float*)d_in[9];
  const float* mu2 = (const float*)d_in[10];
  const float* va2 = (const float*)d_in[11];
  const float* W2  = (const float*)d_in[12];
  const float* c2  = (const float*)d_in[13];
  const float* g3  = (const float*)d_in[14];
  const float* be3 = (const float*)d_in[15];
  const float* mu3 = (const float*)d_in[16];
  const float* va3 = (const float*)d_in[17];
  const float* W3  = (const float*)d_in[18];
  const float* c3  = (const float*)d_in[19];

  // ws layout (63.5 MB): W1t | W23t | params | z2T | z3T | big(z1T ∪ outT)
  unsigned short* W1t  = (unsigned short*)d_ws;
  unsigned short* W23t = W1t + 53248;
  float*          prm  = (float*)(W23t + 212992);
  unsigned short* z2T  = (unsigned short*)(prm + 512);
  unsigned short* z3T  = z2T + ZTOT;
  unsigned short* big  = z3T + ZTOT;       // z1T (read in gemm1) aliases outT (written in gemm2)
  unsigned short* z1T  = big;
  unsigned short* outT = big;

  prep_p<<<1, 128, 0, stream>>>(g1, be1, mu1, va1, c1, g2, be2, mu2, va2, c2,
                                g3, be3, mu3, va3, c3, prm);
  prep_w<<<80, 256, 0, stream>>>(W1, W2, W3, W1t, W23t);
  t_in<<<2048, 256, 0, stream>>>(x, prm, z1T, z3T);
  gemm1<<<960, 256, 0, stream>>>(W1t, z1T, nei, prm, z2T);
  gemm2<<<960, 256, 0, stream>>>(W23t, z2T, z3T, nei, prm, outT);
  t_out<<<2048, 256, 0, stream>>>(outT, (float*)d_out);
}

// Round 6
// 249.584 us; speedup vs baseline: 1.6986x; 1.0386x over previous
//
#include <hip/hip_runtime.h>
#include <hip/hip_bf16.h>

// Residual_Comb_Conv: B=2048, C_IN=64, C_MID=64, C_OUT=128, R=60, K=13
// R6: R5 structure +
//  - XCD-locality swizzle: bid = r*16 + btile (bid%8 = btile%8) so all blocks
//    of one btile share an XCD/L2 -> z-slice working set (~2.3 MB) stays hot.
//  - XOR-swizzled unpadded LDS tiles (chunk j of row rr at j^(rr&7)):
//    staging writes AND fragment reads hit all 32 banks at capacity -> no
//    conflicts, no pad waste (gemm2 LDS 64 KB, gemm1 80 KB -> 2 blocks/CU).
//  - gemm1: block = (btile, r-pair): A tile staged once, shared by both r's.
//  - prep_p merged into prep_w.

typedef __attribute__((ext_vector_type(8))) short bf16x8;
typedef __attribute__((ext_vector_type(4))) float f32x4;
typedef __attribute__((ext_vector_type(4))) unsigned short us4;
typedef __attribute__((ext_vector_type(8))) unsigned short us8;

#define EPSV 1e-5f
#define PLANE 131072           // 2048*64 shorts per z plane
#define ZTOT  7864320          // 60*PLANE

__device__ __forceinline__ unsigned short f2bf(float f) {
  unsigned int u = __builtin_bit_cast(unsigned int, f);
  u += 0x7FFFu + ((u >> 16) & 1u);   // round-to-nearest-even
  return (unsigned short)(u >> 16);
}
__device__ __forceinline__ float bf2f(unsigned short s) {
  unsigned int u = ((unsigned int)s) << 16;
  return __builtin_bit_cast(float, u);
}

// ---- prep: weights -> bf16 transposed layouts; last block also folds BN params
// params: [a1|b1|a3|b3|a2|b2p] (6*64) + cc (128) = 512 floats
__global__ void prep_w(const float* __restrict__ W1, const float* __restrict__ W2,
                       const float* __restrict__ W3,
                       const float* __restrict__ g1, const float* __restrict__ be1,
                       const float* __restrict__ mu1, const float* __restrict__ va1,
                       const float* __restrict__ c1,
                       const float* __restrict__ g2, const float* __restrict__ be2,
                       const float* __restrict__ mu2, const float* __restrict__ va2,
                       const float* __restrict__ c2,
                       const float* __restrict__ g3, const float* __restrict__ be3,
                       const float* __restrict__ mu3, const float* __restrict__ va3,
                       const float* __restrict__ c3,
                       unsigned short* __restrict__ W1t,
                       unsigned short* __restrict__ W23t,
                       float* __restrict__ params) {
  int t = blockIdx.x * 256 + threadIdx.x;
  if (t < 4096) {                        // W1: 64*64 (o,c) rows
    int o = t >> 6, c = t & 63;
    const float* src = W1 + (o * 64 + c) * 13;
    unsigned short* dst = W1t + o * 832 + c;
    #pragma unroll
    for (int ks = 0; ks < 13; ks++) dst[ks * 64] = f2bf(src[ks]);
  } else if (t < 20480) {                // W2,W3: 2*128*64 rows
    int idx = t - 4096;
    int half = idx >> 13;                // 0 -> W2, 1 -> W3
    int o = (idx >> 6) & 127, c = idx & 63;
    const float* src = (half ? W3 : W2) + (o * 64 + c) * 13;
    unsigned short* dst = W23t + o * 1664 + half * 13 * 64 + c;
    #pragma unroll
    for (int ks = 0; ks < 13; ks++) dst[ks * 64] = f2bf(src[ks]);
  }
  if (blockIdx.x == 79) {
    int u = threadIdx.x;
    if (u < 64) {
      float a1v = g1[u] * rsqrtf(va1[u] + EPSV);
      params[u]       = a1v;
      params[64 + u]  = be1[u] - mu1[u] * a1v;
      float a3v = g3[u] * rsqrtf(va3[u] + EPSV);
      params[128 + u] = a3v;
      params[192 + u] = be3[u] - mu3[u] * a3v;
      float a2v = g2[u] * rsqrtf(va2[u] + EPSV);
      params[256 + u] = a2v;
      params[320 + u] = be2[u] - mu2[u] * a2v + a2v * c1[u];  // fold conv1 bias
    }
    if (u < 128) params[384 + u] = c2[u] + c3[u];
  }
}

// ---- transpose-in: x[b][c][r] f32 -> z1T/z3T[r][b][c] bf16 with act1/act3
__global__ __launch_bounds__(256) void t_in(const float* __restrict__ x,
                                            const float* __restrict__ params,
                                            unsigned short* __restrict__ z1T,
                                            unsigned short* __restrict__ z3T) {
  __shared__ float xt[64 * 61];
  __shared__ float prm[256];
  const int b = blockIdx.x, t = threadIdx.x;
  prm[t] = params[t];                       // a1|b1|a3|b3
  for (int i = t; i < 3840; i += 256) {
    int c = i / 60;
    xt[c * 61 + (i - c * 60)] = x[b * 3840 + i];
  }
  __syncthreads();
  if (t < 240) {
    int r = t >> 2, g = t & 3, c0 = g << 4;
    us8 z1v0, z1v1, z3v0, z3v1;
    #pragma unroll
    for (int j = 0; j < 8; j++) {
      int c = c0 + j;
      float v = xt[c * 61 + r];
      z1v0[j] = f2bf(fmaxf(fmaf(v, prm[c], prm[64 + c]), 0.f));
      z3v0[j] = f2bf(fmaxf(fmaf(v, prm[128 + c], prm[192 + c]), 0.f));
    }
    #pragma unroll
    for (int j = 0; j < 8; j++) {
      int c = c0 + 8 + j;
      float v = xt[c * 61 + r];
      z1v1[j] = f2bf(fmaxf(fmaf(v, prm[c], prm[64 + c]), 0.f));
      z3v1[j] = f2bf(fmaxf(fmaf(v, prm[128 + c], prm[192 + c]), 0.f));
    }
    int idx = (r * 2048 + b) * 64 + c0;
    *(us8*)(z1T + idx) = z1v0;  *(us8*)(z1T + idx + 8) = z1v1;
    *(us8*)(z3T + idx) = z3v0;  *(us8*)(z3T + idx + 8) = z3v1;
  }
}

#define MFMA __builtin_amdgcn_mfma_f32_16x16x32_bf16

// ---- gemm1: block = (btile=128 batches, r-pair). C[64 x 128] for each of 2 r's.
//      A (W1t) staged once, shared. Waves: (rsel = w>>1, nhh = w&1); wave tile
//      64 rows x 64 cols = 4m x 4n of 16x16x32.
__global__ __launch_bounds__(256, 2) void gemm1(const unsigned short* __restrict__ W1t,
                                                const unsigned short* __restrict__ z1T,
                                                const int* __restrict__ nei,
                                                const float* __restrict__ params,
                                                unsigned short* __restrict__ z2T) {
  __shared__ unsigned short As[2][4096];        // 64 x 64 per buf
  __shared__ unsigned short Bs[2][2][8192];     // [buf][r] 128 x 64

  const int bid = blockIdx.x;
  const int rp = bid >> 4, btile = bid & 15;    // bid%8 = btile%8 -> XCD locality
  const int b0 = btile << 7;
  const int rA = rp * 2, rB = rA + 1;
  const int t = threadIdx.x, wave = t >> 6, lane = t & 63;
  const int quad = lane >> 4, nl = lane & 15;
  const int rsel = wave >> 1, nhh = wave & 1;

  int pl0[13], pl1[13];
  #pragma unroll
  for (int q = 0; q < 13; q++) { pl0[q] = nei[rA * 13 + q]; pl1[q] = nei[rB * 13 + q]; }

  const int trow = t >> 3, tj = t & 7;
  const int sw8 = ((tj ^ (trow & 7)) << 3);     // XOR-swizzled chunk (shorts)
  const unsigned short* gA = W1t + trow * 832 + tj * 8;
  const unsigned short* gB = z1T + (b0 + trow) * 64 + tj * 8;
  unsigned short* lA = &As[0][trow * 64 + sw8];
  unsigned short* lB0 = &Bs[0][0][trow * 64 + sw8];
  unsigned short* lB1 = &Bs[0][1][trow * 64 + sw8];

  // stage kq=0 into buffer 0
  {
    us8 va0 = *(const us8*)(gA);
    us8 va1 = *(const us8*)(gA + 32 * 832);
    const unsigned short* g0 = gB + pl0[0] * PLANE;
    const unsigned short* g1p = gB + pl1[0] * PLANE;
    us8 b00 = *(const us8*)(g0);
    us8 b01 = *(const us8*)(g0 + 2048);
    us8 b02 = *(const us8*)(g0 + 4096);
    us8 b03 = *(const us8*)(g0 + 6144);
    us8 b10 = *(const us8*)(g1p);
    us8 b11 = *(const us8*)(g1p + 2048);
    us8 b12 = *(const us8*)(g1p + 4096);
    us8 b13 = *(const us8*)(g1p + 6144);
    *(us8*)(lA) = va0;  *(us8*)(lA + 2048) = va1;
    *(us8*)(lB0) = b00; *(us8*)(lB0 + 2048) = b01;
    *(us8*)(lB0 + 4096) = b02; *(us8*)(lB0 + 6144) = b03;
    *(us8*)(lB1) = b10; *(us8*)(lB1 + 2048) = b11;
    *(us8*)(lB1 + 4096) = b12; *(us8*)(lB1 + 6144) = b13;
  }
  __syncthreads();

  const int c0 = ((quad ^ (nl & 7)) << 3);      // physical chunk for logical quad
  f32x4 acc[4][4] = {};
  #pragma unroll 1
  for (int kq = 0; kq < 13; kq++) {
    const int bf = kq & 1;
    us8 va0, va1, b00, b01, b02, b03, b10, b11, b12, b13;
    if (kq < 12) {
      const unsigned short* ga = gA + (kq + 1) * 64;
      va0 = *(const us8*)(ga);
      va1 = *(const us8*)(ga + 32 * 832);
      const unsigned short* g0 = gB + pl0[kq + 1] * PLANE;
      const unsigned short* g1p = gB + pl1[kq + 1] * PLANE;
      b00 = *(const us8*)(g0);        b01 = *(const us8*)(g0 + 2048);
      b02 = *(const us8*)(g0 + 4096); b03 = *(const us8*)(g0 + 6144);
      b10 = *(const us8*)(g1p);        b11 = *(const us8*)(g1p + 2048);
      b12 = *(const us8*)(g1p + 4096); b13 = *(const us8*)(g1p + 6144);
    }
    const unsigned short* Ab = &As[bf][nl * 64];
    const unsigned short* Bb = &Bs[bf][rsel][(nhh * 64 + nl) * 64];
    bf16x8 af[4][2], bfr[4][2];
    #pragma unroll
    for (int mt = 0; mt < 4; mt++) {
      af[mt][0] = *(const bf16x8*)(Ab + mt * 1024 + c0);
      af[mt][1] = *(const bf16x8*)(Ab + mt * 1024 + (c0 ^ 32));
    }
    #pragma unroll
    for (int nt = 0; nt < 4; nt++) {
      bfr[nt][0] = *(const bf16x8*)(Bb + nt * 1024 + c0);
      bfr[nt][1] = *(const bf16x8*)(Bb + nt * 1024 + (c0 ^ 32));
    }
    #pragma unroll
    for (int h = 0; h < 2; h++)
      #pragma unroll
      for (int mt = 0; mt < 4; mt++)
        #pragma unroll
        for (int nt = 0; nt < 4; nt++)
          acc[mt][nt] = MFMA(af[mt][h], bfr[nt][h], acc[mt][nt], 0, 0, 0);
    if (kq < 12) {
      unsigned short* la = lA + (bf ^ 1) * 4096;
      unsigned short* l0 = lB0 + (bf ^ 1) * 16384;
      unsigned short* l1 = lB1 + (bf ^ 1) * 16384;
      *(us8*)(la) = va0;  *(us8*)(la + 2048) = va1;
      *(us8*)(l0) = b00; *(us8*)(l0 + 2048) = b01;
      *(us8*)(l0 + 4096) = b02; *(us8*)(l0 + 6144) = b03;
      *(us8*)(l1) = b10; *(us8*)(l1 + 2048) = b11;
      *(us8*)(l1 + 4096) = b12; *(us8*)(l1 + 6144) = b13;
    }
    __syncthreads();
  }

  // epilogue: act2 -> z2T[r][b][o]
  const int rr = rA + rsel;
  #pragma unroll
  for (int mt = 0; mt < 4; mt++) {
    int ob = mt * 16 + quad * 4;
    f32x4 av = *(const f32x4*)(params + 256 + ob);
    f32x4 bv = *(const f32x4*)(params + 320 + ob);
    #pragma unroll
    for (int nt = 0; nt < 4; nt++) {
      int col = b0 + nhh * 64 + nt * 16 + nl;
      f32x4 a = acc[mt][nt];
      us4 w;
      w.x = f2bf(fmaxf(fmaf(a[0], av[0], bv[0]), 0.f));
      w.y = f2bf(fmaxf(fmaf(a[1], av[1], bv[1]), 0.f));
      w.z = f2bf(fmaxf(fmaf(a[2], av[2], bv[2]), 0.f));
      w.w = f2bf(fmaxf(fmaf(a[3], av[3], bv[3]), 0.f));
      *(us4*)(z2T + (rr * 2048 + col) * 64 + ob) = w;
    }
  }
}

// ---- gemm2: block = (btile=128, r): C[128 x 128] = W23t . [z2T|z3T]-panels + cc
//      waves: (mh = w>>1, nh = w&1), wave tile 64 x 64 = 4m x 4n.
__global__ __launch_bounds__(256, 2) void gemm2(const unsigned short* __restrict__ W23t,
                                                const unsigned short* __restrict__ z2T,
                                                const unsigned short* __restrict__ z3T,
                                                const int* __restrict__ nei,
                                                const float* __restrict__ params,
                                                unsigned short* __restrict__ outT) {
  __shared__ unsigned short As[2][8192];     // 128 x 64 per buf
  __shared__ unsigned short Bs[2][8192];

  const int bid = blockIdx.x;
  const int r = bid >> 4, btile = bid & 15;  // bid%8 = btile%8 -> XCD locality
  const int b0 = btile << 7;
  const int t = threadIdx.x, wave = t >> 6, lane = t & 63;
  const int quad = lane >> 4, nl = lane & 15;
  const int mh = wave >> 1, nh = wave & 1;

  int pl[13];
  #pragma unroll
  for (int q = 0; q < 13; q++) pl[q] = nei[r * 13 + q];

  const int trow = t >> 3, tj = t & 7;
  const int sw8 = ((tj ^ (trow & 7)) << 3);
  const unsigned short* gA  = W23t + trow * 1664 + tj * 8;
  const unsigned short* gB2 = z2T + (b0 + trow) * 64 + tj * 8;
  const unsigned short* gB3 = z3T + (b0 + trow) * 64 + tj * 8;
  unsigned short* lA = &As[0][trow * 64 + sw8];
  unsigned short* lB = &Bs[0][trow * 64 + sw8];

  // stage kq=0 into buffer 0
  {
    us8 va0 = *(const us8*)(gA);
    us8 va1 = *(const us8*)(gA + 32 * 1664);
    us8 va2 = *(const us8*)(gA + 64 * 1664);
    us8 va3 = *(const us8*)(gA + 96 * 1664);
    const unsigned short* gb = gB2 + pl[0] * PLANE;
    us8 vb0 = *(const us8*)(gb);
    us8 vb1 = *(const us8*)(gb + 2048);
    us8 vb2 = *(const us8*)(gb + 4096);
    us8 vb3 = *(const us8*)(gb + 6144);
    *(us8*)(lA) = va0;        *(us8*)(lA + 2048) = va1;
    *(us8*)(lA + 4096) = va2; *(us8*)(lA + 6144) = va3;
    *(us8*)(lB) = vb0;        *(us8*)(lB + 2048) = vb1;
    *(us8*)(lB + 4096) = vb2; *(us8*)(lB + 6144) = vb3;
  }
  __syncthreads();

  const int c0 = ((quad ^ (nl & 7)) << 3);
  f32x4 acc[4][4] = {};
  #pragma unroll 1
  for (int kq = 0; kq < 26; kq++) {
    const int bf = kq & 1;
    us8 va0, va1, va2, va3, vb0, vb1, vb2, vb3;
    if (kq < 25) {
      const int kn = kq + 1;
      const unsigned short* ga = gA + kn * 64;
      va0 = *(const us8*)(ga);
      va1 = *(const us8*)(ga + 32 * 1664);
      va2 = *(const us8*)(ga + 64 * 1664);
      va3 = *(const us8*)(ga + 96 * 1664);
      const unsigned short* gb = (kn < 13) ? (gB2 + pl[kn] * PLANE)
                                           : (gB3 + pl[kn - 13] * PLANE);
      vb0 = *(const us8*)(gb);
      vb1 = *(const us8*)(gb + 2048);
      vb2 = *(const us8*)(gb + 4096);
      vb3 = *(const us8*)(gb + 6144);
    }
    const unsigned short* Ab = &As[bf][(mh * 64 + nl) * 64];
    const unsigned short* Bb = &Bs[bf][(nh * 64 + nl) * 64];
    bf16x8 af[4][2], bfr[4][2];
    #pragma unroll
    for (int mt = 0; mt < 4; mt++) {
      af[mt][0] = *(const bf16x8*)(Ab + mt * 1024 + c0);
      af[mt][1] = *(const bf16x8*)(Ab + mt * 1024 + (c0 ^ 32));
    }
    #pragma unroll
    for (int nt = 0; nt < 4; nt++) {
      bfr[nt][0] = *(const bf16x8*)(Bb + nt * 1024 + c0);
      bfr[nt][1] = *(const bf16x8*)(Bb + nt * 1024 + (c0 ^ 32));
    }
    #pragma unroll
    for (int h = 0; h < 2; h++)
      #pragma unroll
      for (int mt = 0; mt < 4; mt++)
        #pragma unroll
        for (int nt = 0; nt < 4; nt++)
          acc[mt][nt] = MFMA(af[mt][h], bfr[nt][h], acc[mt][nt], 0, 0, 0);
    if (kq < 25) {
      unsigned short* la = lA + (bf ^ 1) * 8192;
      unsigned short* lb = lB + (bf ^ 1) * 8192;
      *(us8*)(la) = va0;        *(us8*)(la + 2048) = va1;
      *(us8*)(la + 4096) = va2; *(us8*)(la + 6144) = va3;
      *(us8*)(lb) = vb0;        *(us8*)(lb + 2048) = vb1;
      *(us8*)(lb + 4096) = vb2; *(us8*)(lb + 6144) = vb3;
    }
    __syncthreads();
  }

  // epilogue: + cc -> outT[r][b][o] bf16
  #pragma unroll
  for (int mt = 0; mt < 4; mt++) {
    int ob = mh * 64 + mt * 16 + quad * 4;
    f32x4 cv = *(const f32x4*)(params + 384 + ob);
    #pragma unroll
    for (int nt = 0; nt < 4; nt++) {
      int col = b0 + nh * 64 + nt * 16 + nl;
      f32x4 a = acc[mt][nt];
      us4 w;
      w.x = f2bf(a[0] + cv[0]);
      w.y = f2bf(a[1] + cv[1]);
      w.z = f2bf(a[2] + cv[2]);
      w.w = f2bf(a[3] + cv[3]);
      *(us4*)(outT + (r * 2048 + col) * 128 + ob) = w;
    }
  }
}

// ---- transpose-out: outT[r][b][o] bf16 -> out[b][o][r] f32
__global__ __launch_bounds__(256) void t_out(const unsigned short* __restrict__ outT,
                                             float* __restrict__ out) {
  __shared__ float ot[60 * 129];
  const int b = blockIdx.x, t = threadIdx.x;
  for (int i = t; i < 1920; i += 256) {
    int r = i >> 5, og = (i & 31) << 2;
    us4 v = *(const us4*)(outT + (r * 2048 + b) * 128 + og);
    ot[r * 129 + og + 0] = bf2f(v.x);
    ot[r * 129 + og + 1] = bf2f(v.y);
    ot[r * 129 + og + 2] = bf2f(v.z);
    ot[r * 129 + og + 3] = bf2f(v.w);
  }
  __syncthreads();
  int o = t >> 1, s = t & 1;
  float* dst = out + b * 7680 + o * 60 + s * 30;
  #pragma unroll
  for (int j = 0; j < 30; j++) dst[j] = ot[(s * 30 + j) * 129 + o];
}

extern "C" void kernel_launch(void* const* d_in, const int* in_sizes, int n_in,
                              void* d_out, int out_size, void* d_ws, size_t ws_size,
                              hipStream_t stream) {
  const float* x   = (const float*)d_in[0];
  const int*   nei = (const int*)d_in[1];
  const float* g1  = (const float*)d_in[2];
  const float* be1 = (const float*)d_in[3];
  const float* mu1 = (const float*)d_in[4];
  const float* va1 = (const float*)d_in[5];
  const float* W1  = (const float*)d_in[6];
  const float* c1  = (const float*)d_in[7];
  const float* g2  = (const float*)d_in[8];
  const float* be2 = (const float*)d_in[9];
  const float* mu2 = (const float*)d_in[10];
  const float* va2 = (const float*)d_in[11];
  const float* W2  = (const float*)d_in[12];
  const float* c2  = (const float*)d_in[13];
  const float* g3  = (const float*)d_in[14];
  const float* be3 = (const float*)d_in[15];
  const float* mu3 = (const float*)d_in[16];
  const float* va3 = (const float*)d_in[17];
  const float* W3  = (const float*)d_in[18];
  const float* c3  = (const float*)d_in[19];

  // ws layout (63.5 MB): W1t | W23t | params | z2T | z3T | big(z1T ∪ outT)
  unsigned short* W1t  = (unsigned short*)d_ws;
  unsigned short* W23t = W1t + 53248;
  float*          prm  = (float*)(W23t + 212992);
  unsigned short* z2T  = (unsigned short*)(prm + 512);
  unsigned short* z3T  = z2T + ZTOT;
  unsigned short* big  = z3T + ZTOT;       // z1T (read in gemm1) aliases outT (written in gemm2)
  unsigned short* z1T  = big;
  unsigned short* outT = big;

  prep_w<<<80, 256, 0, stream>>>(W1, W2, W3,
                                 g1, be1, mu1, va1, c1,
                                 g2, be2, mu2, va2, c2,
                                 g3, be3, mu3, va3, c3,
                                 W1t, W23t, prm);
  t_in<<<2048, 256, 0, stream>>>(x, prm, z1T, z3T);
  gemm1<<<480, 256, 0, stream>>>(W1t, z1T, nei, prm, z2T);
  gemm2<<<960, 256, 0, stream>>>(W23t, z2T, z3T, nei, prm, outT);
  t_out<<<2048, 256, 0, stream>>>(outT, (float*)d_out);
}